// Round 8
// baseline (123.068 us; speedup 1.0000x reference)
//
#include <hip/hip_runtime.h>
#include <hip/hip_bf16.h>

#define NROW 8192   // B*A = 64*128
#define INC  128
#define OUTC 64
#define BG   16     // key-split factor

// Q is pre-scaled by log2(e)/sqrt(64) at projection time, so attention
// computes p = exp2(q'.k) with a single v_exp_f32 per score.
#define QSCALE 0.18033688011112042f

typedef __bf16 bf16x8 __attribute__((ext_vector_type(8)));
typedef __bf16 bf16x4 __attribute__((ext_vector_type(4)));
typedef short  s16x4  __attribute__((ext_vector_type(4)));
typedef short  s16x8  __attribute__((ext_vector_type(8)));
typedef float  f32x4  __attribute__((ext_vector_type(4)));

static __device__ __forceinline__ f32x4 mfma16(bf16x8 a, bf16x8 b, f32x4 c) {
    return __builtin_amdgcn_mfma_f32_16x16x32_bf16(a, b, c, 0, 0, 0);
}
// 16x16x16 bf16 (K=16). C/D of S^T IS the A-operand layout of P for PV.
static __device__ __forceinline__ f32x4 mfma1k(s16x4 a, s16x4 b, f32x4 c) {
    return __builtin_amdgcn_mfma_f32_16x16x16bf16_1k(a, b, c, 0, 0, 0);
}

static __device__ __forceinline__ bf16x8 cvt8(float4 lo, float4 hi) {
    bf16x8 r;
    r[0] = (__bf16)lo.x; r[1] = (__bf16)lo.y; r[2] = (__bf16)lo.z; r[3] = (__bf16)lo.w;
    r[4] = (__bf16)hi.x; r[5] = (__bf16)hi.y; r[6] = (__bf16)hi.z; r[7] = (__bf16)hi.w;
    return r;
}
static __device__ __forceinline__ s16x4 vlo(s16x8 x) {
    return __builtin_shufflevector(x, x, 0, 1, 2, 3);
}
static __device__ __forceinline__ s16x4 vhi(s16x8 x) {
    return __builtin_shufflevector(x, x, 4, 5, 6, 7);
}

// ---------------------------------------------------------------------------
// Kernel 1: projection via MFMA. grid = 256 = b(64) x aq(4), 1 block/CU.
// Slab staged once; 12 n-tiles (3 mats x 4) spread 3-per-wave.
//
// ROUND 8: vbf layout changed to N-PAIR-INTERLEAVED so attention's V loads
// are 16B instead of 8B. Element addr for (key16grp g, k'=key&15, outc c):
//   g*1024 + (c_hi>>1)*512 + (c&15)*32 + (k'>>2)*16 + (c_hi&1)*4 + (k'&3)
// where c_hi = c>>4. One dwordx4 at [g][p][c&15][quad] yields the s16x4
// B-frags for n=2p and n=2p+1 back-to-back.
__global__ __launch_bounds__(256) void proj_kernel(
    const float* __restrict__ feat,
    const float* __restrict__ Wq, const float* __restrict__ bq,
    const float* __restrict__ Wk, const float* __restrict__ bk,
    const float* __restrict__ Wv, const float* __restrict__ bv,
    __hip_bfloat16* __restrict__ qbf, __hip_bfloat16* __restrict__ kbf,
    __hip_bfloat16* __restrict__ vbf, __hip_bfloat16* __restrict__ vnb)
{
    __shared__ float slab[32 * 132];
    __shared__ float vbuf[32 * 66];
    __shared__ float invb[32];

    const int blk = blockIdx.x;
    const int b   = blk >> 2;
    const int a0  = (blk & 3) * 32;
    const int r0  = b * 128 + a0;
    const float* fb = feat + (size_t)b * INC * 128;

    for (int i = threadIdx.x; i < 32 * 128; i += 256) {
        int c = i >> 5, a = i & 31;
        slab[a * 132 + c] = fb[c * 128 + a0 + a];
    }
    __syncthreads();

    const int w    = threadIdx.x >> 6;
    const int lane = threadIdx.x & 63;
    const int l16  = lane & 15;
    const int quad = lane >> 4;

    f32x4 acc[3][2];
    #pragma unroll
    for (int t = 0; t < 3; ++t)
        #pragma unroll
        for (int u = 0; u < 2; ++u)
            acc[t][u] = (f32x4){0.f, 0.f, 0.f, 0.f};

    #pragma unroll
    for (int kc = 0; kc < 4; ++kc) {
        const int k0 = kc * 32 + quad * 8;
        bf16x8 afr[2];
        #pragma unroll
        for (int u = 0; u < 2; ++u) {
            const float* ar = slab + (u * 16 + l16) * 132 + k0;
            afr[u] = cvt8(*(const float4*)ar, *(const float4*)(ar + 4));
        }
        #pragma unroll
        for (int t = 0; t < 3; ++t) {
            const int tile = w * 3 + t;
            const int mat  = tile >> 2;
            const float* W = (mat == 0) ? Wq : (mat == 1) ? Wk : Wv;
            const float* wr = W + ((tile & 3) * 16 + l16) * INC + k0;
            bf16x8 bfr = cvt8(*(const float4*)wr, *(const float4*)(wr + 4));
            #pragma unroll
            for (int u = 0; u < 2; ++u)
                acc[t][u] = mfma16(afr[u], bfr, acc[t][u]);
        }
    }

    #pragma unroll
    for (int t = 0; t < 3; ++t) {
        const int tile = w * 3 + t;
        const int mat  = tile >> 2;
        const int nt   = tile & 3;
        const float* bias = (mat == 0) ? bq : (mat == 1) ? bk : bv;
        const float bl = bias[nt * 16 + l16];
        if (mat < 2) {
            const float sc = (mat == 0) ? QSCALE : 1.0f;
            __hip_bfloat16* dst = mat ? kbf : qbf;
            #pragma unroll
            for (int u = 0; u < 2; ++u) {
                const int base = ((((r0 >> 4) + u) * 4 + nt) << 8) + l16;
                #pragma unroll
                for (int r = 0; r < 4; ++r)
                    dst[base + (quad * 4 + r) * 16] = __float2bfloat16((acc[t][u][r] + bl) * sc);
            }
        } else {
            #pragma unroll
            for (int u = 0; u < 2; ++u)
                #pragma unroll
                for (int r = 0; r < 4; ++r)
                    vbuf[(u * 16 + quad * 4 + r) * 66 + nt * 16 + l16] = acc[t][u][r] + bl;
        }
    }
    __syncthreads();

    // ---- V normalize phase (block-wide) ----
    const int rl = threadIdx.x >> 3;
    const int jj = threadIdx.x & 7;
    float ss = 0.f;
    #pragma unroll
    for (int i = 0; i < 8; ++i) {
        float x = vbuf[rl * 66 + jj * 8 + i];
        ss += x * x;
    }
    ss += __shfl_xor(ss, 1, 64);
    ss += __shfl_xor(ss, 2, 64);
    ss += __shfl_xor(ss, 4, 64);
    if (jj == 0) invb[rl] = rsqrtf(fmaxf(ss, 1e-24f));
    __syncthreads();
    float inv = invb[rl];
    bf16x8 vp;
    #pragma unroll
    for (int i = 0; i < 8; ++i)
        vp[i] = (__bf16)(vbuf[rl * 66 + jj * 8 + i] * inv);
    *(bf16x8*)(vnb + (size_t)(r0 + rl) * 64 + jj * 8) = vp;

    // ---- vbf write in N-PAIR-INTERLEAVED layout ----
    const int tl = threadIdx.x & 15;
    const int n  = (threadIdx.x >> 4) & 3;
    const int s_ = threadIdx.x >> 6;
    bf16x8 pack;   // keys s_*8 + j (j=0..7), outc col = n*16 + tl
    #pragma unroll
    for (int j = 0; j < 8; ++j) {
        int key = s_ * 8 + j;
        pack[j] = (__bf16)(vbuf[key * 66 + n * 16 + tl] * invb[key]);
    }
    const int hblk = (r0 >> 4) + (s_ >> 1);
    const int eb = hblk * 1024 + (n >> 1) * 512 + tl * 32 + (s_ & 1) * 16 + (n & 1) * 4;
    bf16x4 plo = __builtin_shufflevector(pack, pack, 0, 1, 2, 3);
    bf16x4 phi = __builtin_shufflevector(pack, pack, 4, 5, 6, 7);
    *(bf16x4*)(vbf + eb)     = plo;   // keys j=0..3
    *(bf16x4*)(vbf + eb + 8) = phi;   // keys j=4..7
}

// ---------------------------------------------------------------------------
// Kernel 2: attention. grid = 512 = qb(32) x bg(16); block = 256 q-rows x
// 512 keys; 2 blocks/CU = 2 waves/SIMD (r5 optimum). 64 q-rows per wave.
//
// ROUND 8: V loads widened 8x8B -> 4x16B via the n-pair-interleaved vbf
// layout (VMEM instrs/iter 12 -> 8; the confirmed per-CU VMEM-issue model
// predicts ~ -20-25% attn time at constant registers/waves).
#define ATTN_ITER(K00,K01,K10,K11, NK00,NK01,NK10,NK11,                      \
                  W0,W1,W2,W3, NW0,NW1,NW2,NW3)                              \
    do {                                                                     \
        NW0 = *(const s16x8*)(vp);              /* h0: n0|n1 */              \
        NW1 = *(const s16x8*)(vp + 1024);       /* h0: n2|n3 */              \
        NW2 = *(const s16x8*)(vp + 2048);       /* h1: n0|n1 */              \
        NW3 = *(const s16x8*)(vp + 3072);       /* h1: n2|n3 */              \
        NK00 = *(const bf16x8*)(kp);                                         \
        NK01 = *(const bf16x8*)(kp + 1024);                                  \
        NK10 = *(const bf16x8*)(kp + 2048);                                  \
        NK11 = *(const bf16x8*)(kp + 3072);                                  \
        vp += 4096; kp += 4096;                                              \
        const f32x4 zero = (f32x4){0.f, 0.f, 0.f, 0.f};                      \
        _Pragma("unroll")                                                    \
        for (int u = 0; u < 4; ++u) {                                        \
            f32x4 s0 = mfma16(K00, qf32[u][0], zero);                        \
            s0       = mfma16(K01, qf32[u][1], s0);                          \
            f32x4 s1 = mfma16(K10, qf32[u][0], zero);                        \
            s1       = mfma16(K11, qf32[u][1], s1);                          \
            union { bf16x4 v; s16x4 s; } pf0, pf1;                           \
            _Pragma("unroll")                                                \
            for (int r = 0; r < 4; ++r) {                                    \
                float p0 = __builtin_amdgcn_exp2f(s0[r]);                    \
                float p1 = __builtin_amdgcn_exp2f(s1[r]);                    \
                lp[u] += p0 + p1;                                            \
                pf0.v[r] = (__bf16)p0;                                       \
                pf1.v[r] = (__bf16)p1;                                       \
            }                                                                \
            of[u][0] = mfma1k(pf0.s, vlo(W0), of[u][0]);                     \
            of[u][0] = mfma1k(pf1.s, vlo(W2), of[u][0]);                     \
            of[u][1] = mfma1k(pf0.s, vhi(W0), of[u][1]);                     \
            of[u][1] = mfma1k(pf1.s, vhi(W2), of[u][1]);                     \
            of[u][2] = mfma1k(pf0.s, vlo(W1), of[u][2]);                     \
            of[u][2] = mfma1k(pf1.s, vlo(W3), of[u][2]);                     \
            of[u][3] = mfma1k(pf0.s, vhi(W1), of[u][3]);                     \
            of[u][3] = mfma1k(pf1.s, vhi(W3), of[u][3]);                     \
        }                                                                    \
    } while (0)

__global__ __launch_bounds__(256, 2) void attn_kernel(
    const __hip_bfloat16* __restrict__ qbf,
    const __hip_bfloat16* __restrict__ kbf,
    const __hip_bfloat16* __restrict__ vbf,
    float* __restrict__ Opart, float* __restrict__ lpart)
{
    const int qb    = blockIdx.x >> 4;
    const int bg    = blockIdx.x & 15;
    const int w     = threadIdx.x >> 6;
    const int lane  = threadIdx.x & 63;
    const int l16   = lane & 15;
    const int quad  = lane >> 4;
    const int r0    = qb * 256 + w * 64;              // 64 q-rows per wave
    const int fo32  = l16 * 16 + (quad & 1) * 8;      // K=32 frag elem offset
    const int qh    = quad >> 1;                      // K=32 tile-pair half

    // Q fragments in K=32 form: 4 x 16-row subtiles
    bf16x8 qf32[4][2];
    #pragma unroll
    for (int u = 0; u < 4; ++u)
        #pragma unroll
        for (int p = 0; p < 2; ++p)
            qf32[u][p] = *(const bf16x8*)(qbf +
                ((((r0 >> 4) + u) * 4 + p * 2 + qh) << 8) + fo32);

    f32x4 of[4][4];
    float lp[4] = {0.f, 0.f, 0.f, 0.f};
    #pragma unroll
    for (int u = 0; u < 4; ++u)
        #pragma unroll
        for (int n = 0; n < 4; ++n)
            of[u][n] = (f32x4){0.f, 0.f, 0.f, 0.f};

    // byte pointers: 16-key group = 2048 B, iteration (2 groups) = 4096 B
    const int ck0 = bg * 32;                          // 32 groups = 512 keys
    const char* kp = (const char*)kbf + ck0 * 2048 + qh * 512 + fo32 * 2;
    const char* vp = (const char*)vbf + ck0 * 2048 + l16 * 64 + quad * 16;

    bf16x8 kA00, kA01, kA10, kA11, kB00, kB01, kB10, kB11;
    s16x8  wA0, wA1, wA2, wA3, wB0, wB1, wB2, wB3;

    // prologue: load iteration 0's K and V
    wA0 = *(const s16x8*)(vp);
    wA1 = *(const s16x8*)(vp + 1024);
    wA2 = *(const s16x8*)(vp + 2048);
    wA3 = *(const s16x8*)(vp + 3072);
    kA00 = *(const bf16x8*)(kp);
    kA01 = *(const bf16x8*)(kp + 1024);
    kA10 = *(const bf16x8*)(kp + 2048);
    kA11 = *(const bf16x8*)(kp + 3072);
    vp += 4096; kp += 4096;

    #pragma unroll 1
    for (int body = 0; body < 8; ++body) {
        ATTN_ITER(kA00, kA01, kA10, kA11, kB00, kB01, kB10, kB11,
                  wA0, wA1, wA2, wA3, wB0, wB1, wB2, wB3);
        ATTN_ITER(kB00, kB01, kB10, kB11, kA00, kA01, kA10, kA11,
                  wB0, wB1, wB2, wB3, wA0, wA1, wA2, wA3);
    }

    // per-wave l reduction across quads
    #pragma unroll
    for (int u = 0; u < 4; ++u) {
        float v = lp[u];
        v += __shfl_xor(v, 16, 64);
        v += __shfl_xor(v, 32, 64);
        lp[u] = v;
    }

    // streaming per-wave partial: tile = qb*4 + w owns rows [r0, r0+64)
    const int task = (qb * 4 + w) * 16 + bg;
    float* Ob = Opart + (size_t)task * 4096;
    #pragma unroll
    for (int u = 0; u < 4; ++u)
        #pragma unroll
        for (int n = 0; n < 4; ++n)
            #pragma unroll
            for (int r = 0; r < 4; ++r)
                Ob[(u * 16 + quad * 4 + r) * 64 + n * 16 + l16] = of[u][n][r];
    if (quad == 0) {
        #pragma unroll
        for (int u = 0; u < 4; ++u)
            lpart[task * 64 + u * 16 + l16] = lp[u];
    }
}

// ---------------------------------------------------------------------------
// Kernel 3: combine 16 partials/tile (64-row tiles), divide by l,
// l2-normalize -> qnb (bf16). grid = 2048 x 256. Block 0 also zeroes the
// 16KB output (runs before sim's atomics; saves the memset dispatch).
__global__ __launch_bounds__(256) void combine_kernel(
    const float* __restrict__ Opart, const float* __restrict__ lpart,
    __hip_bfloat16* __restrict__ qnb, float* __restrict__ outz)
{
    if (blockIdx.x == 0) {
        #pragma unroll
        for (int z = 0; z < 4; ++z)
            ((float4*)outz)[threadIdx.x * 4 + z] = (float4){0.f, 0.f, 0.f, 0.f};
    }

    const int r    = blockIdx.x * 4 + (threadIdx.x >> 6);
    const int c    = threadIdx.x & 63;
    const int tile = r >> 6, row = r & 63;
    float acc = 0.f, lsum = 0.f;
    #pragma unroll
    for (int g = 0; g < 16; ++g) {
        int task = tile * 16 + g;
        acc  += Opart[(size_t)task * 4096 + row * 64 + c];
        lsum += lpart[task * 64 + row];
    }
    float q = acc / lsum;
    float ss = q * q;
    ss += __shfl_xor(ss, 1, 64);
    ss += __shfl_xor(ss, 2, 64);
    ss += __shfl_xor(ss, 4, 64);
    ss += __shfl_xor(ss, 8, 64);
    ss += __shfl_xor(ss, 16, 64);
    ss += __shfl_xor(ss, 32, 64);
    qnb[(size_t)r * 64 + c] = __float2bfloat16(q * rsqrtf(fmaxf(ss, 1e-24f)));
}

// ---------------------------------------------------------------------------
// Kernel 4: sim = (1/128) * Vn(64x8192) @ Qn(64x8192)^T, split-K MFMA GEMM.
// grid = 64 blocks x 256: each wave owns ONE 32-k slice (16 MFMAs) -> half
// the serial depth of the 32-block version; atomicAdd merge (4K addresses).
__global__ __launch_bounds__(256) void sim_kernel(
    const __hip_bfloat16* __restrict__ vnb,
    const __hip_bfloat16* __restrict__ qnb,
    float* __restrict__ out)
{
    const int w    = threadIdx.x >> 6;
    const int lane = threadIdx.x & 63;
    const int l16  = lane & 15;
    const int quad = lane >> 4;
    const int k0   = blockIdx.x * 128 + w * 32 + quad * 8;

    f32x4 acc[4][4];
    #pragma unroll
    for (int mi = 0; mi < 4; ++mi)
        #pragma unroll
        for (int ni = 0; ni < 4; ++ni)
            acc[mi][ni] = (f32x4){0.f, 0.f, 0.f, 0.f};

    bf16x8 af[4], bfv[4];
    #pragma unroll
    for (int mi = 0; mi < 4; ++mi)
        af[mi] = *(const bf16x8*)(vnb + (size_t)(mi * 16 + l16) * 8192 + k0);
    #pragma unroll
    for (int ni = 0; ni < 4; ++ni)
        bfv[ni] = *(const bf16x8*)(qnb + (size_t)(ni * 16 + l16) * 8192 + k0);
    #pragma unroll
    for (int mi = 0; mi < 4; ++mi)
        #pragma unroll
        for (int ni = 0; ni < 4; ++ni)
            acc[mi][ni] = mfma16(af[mi], bfv[ni], acc[mi][ni]);

    #pragma unroll
    for (int mi = 0; mi < 4; ++mi)
        #pragma unroll
        for (int ni = 0; ni < 4; ++ni)
            #pragma unroll
            for (int r = 0; r < 4; ++r)
                atomicAdd(&out[(mi * 16 + quad * 4 + r) * 64 + ni * 16 + l16],
                          acc[mi][ni][r] * (1.f / 128.f));
}

// ---------------------------------------------------------------------------
extern "C" void kernel_launch(void* const* d_in, const int* in_sizes, int n_in,
                              void* d_out, int out_size, void* d_ws, size_t ws_size,
                              hipStream_t stream)
{
    const float* feat = (const float*)d_in[0];
    const float* Wq   = (const float*)d_in[1];
    const float* bq   = (const float*)d_in[2];
    const float* Wk   = (const float*)d_in[3];
    const float* bk   = (const float*)d_in[4];
    const float* Wv   = (const float*)d_in[5];
    const float* bv   = (const float*)d_in[6];
    float* out = (float*)d_out;

    const size_t MB = 1u << 20;
    char* ws = (char*)d_ws;
    __hip_bfloat16* qbf = (__hip_bfloat16*)(ws);              // 1 MB (frag-tiled, pre-scaled)
    __hip_bfloat16* kbf = (__hip_bfloat16*)(ws + 1 * MB);     // 1 MB (frag-tiled)
    __hip_bfloat16* vbf = (__hip_bfloat16*)(ws + 2 * MB);     // 1 MB (n-pair-interleaved)
    __hip_bfloat16* vnb = (__hip_bfloat16*)(ws + 3 * MB);     // 1 MB (row-major)
    float* Opart = (float*)(ws + 4 * MB);                     // 32 MB (2048 x 16 KB)
    float* lpart = (float*)(ws + 36 * MB);                    // 512 KB
    __hip_bfloat16* qnb = (__hip_bfloat16*)(ws + 37 * MB);    // 1 MB

    proj_kernel<<<256, 256, 0, stream>>>(feat, Wq, bq, Wk, bk, Wv, bv, qbf, kbf, vbf, vnb);
    attn_kernel<<<512, 256, 0, stream>>>(qbf, kbf, vbf, Opart, lpart);
    combine_kernel<<<2048, 256, 0, stream>>>(Opart, lpart, qnb, out);
    sim_kernel<<<64, 256, 0, stream>>>(vnb, qnb, out);
}

// Round 9
// 121.632 us; speedup vs baseline: 1.0118x; 1.0118x over previous
//
#include <hip/hip_runtime.h>
#include <hip/hip_bf16.h>

#define NROW 8192   // B*A = 64*128
#define INC  128
#define OUTC 64
#define BG   16     // key-split factor

// Q is pre-scaled by log2(e)/sqrt(64) at projection time, so attention
// computes p = exp2(q'.k) with a single v_exp_f32 per score.
#define QSCALE 0.18033688011112042f

typedef __bf16 bf16x8 __attribute__((ext_vector_type(8)));
typedef __bf16 bf16x4 __attribute__((ext_vector_type(4)));
typedef short  s16x4  __attribute__((ext_vector_type(4)));
typedef short  s16x8  __attribute__((ext_vector_type(8)));
typedef float  f32x4  __attribute__((ext_vector_type(4)));

static __device__ __forceinline__ f32x4 mfma16(bf16x8 a, bf16x8 b, f32x4 c) {
    return __builtin_amdgcn_mfma_f32_16x16x32_bf16(a, b, c, 0, 0, 0);
}
// 16x16x16 bf16 (K=16). C/D of S^T IS the A-operand layout of P for PV.
static __device__ __forceinline__ f32x4 mfma1k(s16x4 a, s16x4 b, f32x4 c) {
    return __builtin_amdgcn_mfma_f32_16x16x16bf16_1k(a, b, c, 0, 0, 0);
}

static __device__ __forceinline__ bf16x8 cvt8(float4 lo, float4 hi) {
    bf16x8 r;
    r[0] = (__bf16)lo.x; r[1] = (__bf16)lo.y; r[2] = (__bf16)lo.z; r[3] = (__bf16)lo.w;
    r[4] = (__bf16)hi.x; r[5] = (__bf16)hi.y; r[6] = (__bf16)hi.z; r[7] = (__bf16)hi.w;
    return r;
}
static __device__ __forceinline__ s16x4 vlo(s16x8 x) {
    return __builtin_shufflevector(x, x, 0, 1, 2, 3);
}
static __device__ __forceinline__ s16x4 vhi(s16x8 x) {
    return __builtin_shufflevector(x, x, 4, 5, 6, 7);
}

// ---------------------------------------------------------------------------
// Kernel 1: projection via MFMA. grid = 256 = b(64) x aq(4), 1 block/CU.
// Slab staged once; 12 n-tiles (3 mats x 4) spread 3-per-wave.
//
// ROUND 9: kbf and vbf are written in FRAGMENT-LINEAR layout: within each
// 4 KB chunk (32 keys), sub-block sb (1 KB) holds the wave's fragment for
// (key-half h, K32-half p) = sb, and lane L's 16 bytes sit at L*16. This
// makes attention's LDS staging a linear copy (tid*16) and every
// ds_read_b128 conflict-free (lane*16).
//   K: new_el = (g>>1)*2048 + (g&1)*1024 + (nt>>1)*512
//              + ((nt&1)*2 + (oc>>3))*128 + kr*8 + (oc&7)
//   V: new_el = (g>>1)*2048 + (g&1)*1024 + (n>>1)*512 + s1*256 + tl*8
//              + (n&1)*4  (+128 for the hi-key half)
__global__ __launch_bounds__(256) void proj_kernel(
    const float* __restrict__ feat,
    const float* __restrict__ Wq, const float* __restrict__ bq,
    const float* __restrict__ Wk, const float* __restrict__ bk,
    const float* __restrict__ Wv, const float* __restrict__ bv,
    __hip_bfloat16* __restrict__ qbf, __hip_bfloat16* __restrict__ kbf,
    __hip_bfloat16* __restrict__ vbf, __hip_bfloat16* __restrict__ vnb)
{
    __shared__ float slab[32 * 132];
    __shared__ float vbuf[32 * 66];
    __shared__ float invb[32];

    const int blk = blockIdx.x;
    const int b   = blk >> 2;
    const int a0  = (blk & 3) * 32;
    const int r0  = b * 128 + a0;
    const float* fb = feat + (size_t)b * INC * 128;

    for (int i = threadIdx.x; i < 32 * 128; i += 256) {
        int c = i >> 5, a = i & 31;
        slab[a * 132 + c] = fb[c * 128 + a0 + a];
    }
    __syncthreads();

    const int w    = threadIdx.x >> 6;
    const int lane = threadIdx.x & 63;
    const int l16  = lane & 15;
    const int quad = lane >> 4;

    f32x4 acc[3][2];
    #pragma unroll
    for (int t = 0; t < 3; ++t)
        #pragma unroll
        for (int u = 0; u < 2; ++u)
            acc[t][u] = (f32x4){0.f, 0.f, 0.f, 0.f};

    #pragma unroll
    for (int kc = 0; kc < 4; ++kc) {
        const int k0 = kc * 32 + quad * 8;
        bf16x8 afr[2];
        #pragma unroll
        for (int u = 0; u < 2; ++u) {
            const float* ar = slab + (u * 16 + l16) * 132 + k0;
            afr[u] = cvt8(*(const float4*)ar, *(const float4*)(ar + 4));
        }
        #pragma unroll
        for (int t = 0; t < 3; ++t) {
            const int tile = w * 3 + t;
            const int mat  = tile >> 2;
            const float* W = (mat == 0) ? Wq : (mat == 1) ? Wk : Wv;
            const float* wr = W + ((tile & 3) * 16 + l16) * INC + k0;
            bf16x8 bfr = cvt8(*(const float4*)wr, *(const float4*)(wr + 4));
            #pragma unroll
            for (int u = 0; u < 2; ++u)
                acc[t][u] = mfma16(afr[u], bfr, acc[t][u]);
        }
    }

    #pragma unroll
    for (int t = 0; t < 3; ++t) {
        const int tile = w * 3 + t;
        const int mat  = tile >> 2;
        const int nt   = tile & 3;
        const float* bias = (mat == 0) ? bq : (mat == 1) ? bk : bv;
        const float bl = bias[nt * 16 + l16];
        if (mat == 0) {
            // Q: original frag-tiled layout, pre-scaled
            #pragma unroll
            for (int u = 0; u < 2; ++u) {
                const int base = ((((r0 >> 4) + u) * 4 + nt) << 8) + l16;
                #pragma unroll
                for (int r = 0; r < 4; ++r)
                    qbf[base + (quad * 4 + r) * 16] =
                        __float2bfloat16((acc[t][u][r] + bl) * QSCALE);
            }
        } else if (mat == 1) {
            // K: fragment-linear layout (see header comment)
            const int kq = (r0 >> 5) * 2048 + (nt >> 1) * 512 +
                           ((nt & 1) * 2 + (l16 >> 3)) * 128 + quad * 32 + (l16 & 7);
            #pragma unroll
            for (int u = 0; u < 2; ++u)
                #pragma unroll
                for (int r = 0; r < 4; ++r)
                    kbf[kq + u * 1024 + r * 8] = __float2bfloat16(acc[t][u][r] + bl);
        } else {
            #pragma unroll
            for (int u = 0; u < 2; ++u)
                #pragma unroll
                for (int r = 0; r < 4; ++r)
                    vbuf[(u * 16 + quad * 4 + r) * 66 + nt * 16 + l16] = acc[t][u][r] + bl;
        }
    }
    __syncthreads();

    // ---- V normalize phase (block-wide) ----
    const int rl = threadIdx.x >> 3;
    const int jj = threadIdx.x & 7;
    float ss = 0.f;
    #pragma unroll
    for (int i = 0; i < 8; ++i) {
        float x = vbuf[rl * 66 + jj * 8 + i];
        ss += x * x;
    }
    ss += __shfl_xor(ss, 1, 64);
    ss += __shfl_xor(ss, 2, 64);
    ss += __shfl_xor(ss, 4, 64);
    if (jj == 0) invb[rl] = rsqrtf(fmaxf(ss, 1e-24f));
    __syncthreads();
    float inv = invb[rl];
    bf16x8 vp;
    #pragma unroll
    for (int i = 0; i < 8; ++i)
        vp[i] = (__bf16)(vbuf[rl * 66 + jj * 8 + i] * inv);
    *(bf16x8*)(vnb + (size_t)(r0 + rl) * 64 + jj * 8) = vp;

    // ---- vbf write in fragment-linear layout ----
    const int tl = threadIdx.x & 15;
    const int n  = (threadIdx.x >> 4) & 3;
    const int s_ = threadIdx.x >> 6;
    bf16x8 pack;   // keys s_*8 + j (j=0..7), outc col = n*16 + tl
    #pragma unroll
    for (int j = 0; j < 8; ++j) {
        int key = s_ * 8 + j;
        pack[j] = (__bf16)(vbuf[key * 66 + n * 16 + tl] * invb[key]);
    }
    const int e1 = (r0 >> 5) * 2048 + (s_ >> 1) * 1024 + (n >> 1) * 512 +
                   (s_ & 1) * 256 + tl * 8 + (n & 1) * 4;
    bf16x4 plo = __builtin_shufflevector(pack, pack, 0, 1, 2, 3);
    bf16x4 phi = __builtin_shufflevector(pack, pack, 4, 5, 6, 7);
    *(bf16x4*)(vbf + e1)       = plo;   // keys j=0..3
    *(bf16x4*)(vbf + e1 + 128) = phi;   // keys j=4..7
}

// ---------------------------------------------------------------------------
// Kernel 2: attention. grid = 512 = qb(32) x bg(16); block = 256 q-rows x
// 512 keys; 2 blocks/CU (r5 optimum tiling, 64 q-rows/wave).
//
// ROUND 9: K/V staged into LDS once per block (r7->r8 proved time tracks
// per-CU L1 LINE-TOUCHES, not VMEM instr count: widening loads was null).
// Previously all 4 waves privately streamed the same 8 KB/iter through L1
// (~8k line-touches/CU); now one linear copy per block (2 dwordx4 + 2
// ds_write_b128 per wave-iter) -> line-touches /4; fragment reads become
// conflict-free ds_read_b128 at lane*16 (fragment-linear global layout).
// Double-buffered, 1 barrier per 32-key chunk.
#define STAGE_W(BUF, KR, VR) do {                                            \
        *(float4*)((BUF) + stb) = KR;                                        \
        *(float4*)((BUF) + 4096 + stb) = VR; } while (0)
#define STAGE_L(KR, VR) do {                                                 \
        KR = *(const float4*)gk; VR = *(const float4*)gv;                    \
        gk += 4096; gv += 4096; } while (0)

#define COMPUTE(BUF) do {                                                    \
    const char* kbp = (BUF);                                                 \
    const char* vbp = (BUF) + 4096;                                          \
    bf16x8 k00 = *(const bf16x8*)(kbp + lb);                                 \
    bf16x8 k01 = *(const bf16x8*)(kbp + lb + 1024);                          \
    bf16x8 k10 = *(const bf16x8*)(kbp + lb + 2048);                          \
    bf16x8 k11 = *(const bf16x8*)(kbp + lb + 3072);                          \
    s16x8 W0 = *(const s16x8*)(vbp + lb);                                    \
    s16x8 W1 = *(const s16x8*)(vbp + lb + 1024);                             \
    s16x8 W2 = *(const s16x8*)(vbp + lb + 2048);                             \
    s16x8 W3 = *(const s16x8*)(vbp + lb + 3072);                             \
    const f32x4 zero = (f32x4){0.f, 0.f, 0.f, 0.f};                          \
    _Pragma("unroll")                                                        \
    for (int u = 0; u < 4; ++u) {                                            \
        f32x4 s0 = mfma16(k00, qf32[u][0], zero);                            \
        s0       = mfma16(k01, qf32[u][1], s0);                              \
        f32x4 s1 = mfma16(k10, qf32[u][0], zero);                            \
        s1       = mfma16(k11, qf32[u][1], s1);                              \
        union { bf16x4 v; s16x4 s; } pf0, pf1;                               \
        _Pragma("unroll")                                                    \
        for (int r = 0; r < 4; ++r) {                                        \
            float p0 = __builtin_amdgcn_exp2f(s0[r]);                        \
            float p1 = __builtin_amdgcn_exp2f(s1[r]);                        \
            lp[u] += p0 + p1;                                                \
            pf0.v[r] = (__bf16)p0;                                           \
            pf1.v[r] = (__bf16)p1;                                           \
        }                                                                    \
        of[u][0] = mfma1k(pf0.s, vlo(W0), of[u][0]);                         \
        of[u][0] = mfma1k(pf1.s, vlo(W2), of[u][0]);                         \
        of[u][1] = mfma1k(pf0.s, vhi(W0), of[u][1]);                         \
        of[u][1] = mfma1k(pf1.s, vhi(W2), of[u][1]);                         \
        of[u][2] = mfma1k(pf0.s, vlo(W1), of[u][2]);                         \
        of[u][2] = mfma1k(pf1.s, vlo(W3), of[u][2]);                         \
        of[u][3] = mfma1k(pf0.s, vhi(W1), of[u][3]);                         \
        of[u][3] = mfma1k(pf1.s, vhi(W3), of[u][3]);                         \
    } } while (0)

__global__ __launch_bounds__(256, 2) void attn_kernel(
    const __hip_bfloat16* __restrict__ qbf,
    const __hip_bfloat16* __restrict__ kbf,
    const __hip_bfloat16* __restrict__ vbf,
    float* __restrict__ Opart, float* __restrict__ lpart)
{
    __shared__ float4 ldsq[2][512];                   // 2 x (4KB K + 4KB V)
    char* bufA = (char*)&ldsq[0][0];
    char* bufB = (char*)&ldsq[1][0];

    const int qb    = blockIdx.x >> 4;
    const int bg    = blockIdx.x & 15;
    const int tid   = threadIdx.x;
    const int w     = tid >> 6;
    const int lane  = tid & 63;
    const int l16   = lane & 15;
    const int quad  = lane >> 4;
    const int r0    = qb * 256 + w * 64;              // 64 q-rows per wave
    const int fo32  = l16 * 16 + (quad & 1) * 8;      // K=32 frag elem offset
    const int qh    = quad >> 1;                      // K=32 tile-pair half
    const int lb    = lane * 16;                      // frag byte offset in LDS
    const int stb   = tid * 16;                       // staging byte offset

    // Q fragments in K=32 form (qbf layout unchanged)
    bf16x8 qf32[4][2];
    #pragma unroll
    for (int u = 0; u < 4; ++u)
        #pragma unroll
        for (int p = 0; p < 2; ++p)
            qf32[u][p] = *(const bf16x8*)(qbf +
                ((((r0 >> 4) + u) * 4 + p * 2 + qh) << 8) + fo32);

    f32x4 of[4][4];
    float lp[4] = {0.f, 0.f, 0.f, 0.f};
    #pragma unroll
    for (int u = 0; u < 4; ++u)
        #pragma unroll
        for (int n = 0; n < 4; ++n)
            of[u][n] = (f32x4){0.f, 0.f, 0.f, 0.f};

    // global staging pointers: chunk = 4 KB = 32 keys; 16 chunks per block
    const char* gk = (const char*)kbf + (size_t)(bg * 16) * 4096 + stb;
    const char* gv = (const char*)vbf + (size_t)(bg * 16) * 4096 + stb;

    float4 ka, va, kb_, vb_;
    STAGE_L(ka, va);                                  // chunk 0
    STAGE_W(bufA, ka, va);
    STAGE_L(kb_, vb_);                                // chunk 1
    __syncthreads();                                  // bufA ready

    #pragma unroll 1
    for (int body = 0; body < 7; ++body) {
        STAGE_W(bufB, kb_, vb_);                      // chunk 2b+1 -> bufB
        STAGE_L(ka, va);                              // chunk 2b+2
        COMPUTE(bufA);                                // chunk 2b
        __syncthreads();
        STAGE_W(bufA, ka, va);                        // chunk 2b+2 -> bufA
        STAGE_L(kb_, vb_);                            // chunk 2b+3
        COMPUTE(bufB);                                // chunk 2b+1
        __syncthreads();
    }
    STAGE_W(bufB, kb_, vb_);                          // chunk 15
    COMPUTE(bufA);                                    // chunk 14
    __syncthreads();
    COMPUTE(bufB);                                    // chunk 15

    // per-wave l reduction across quads
    #pragma unroll
    for (int u = 0; u < 4; ++u) {
        float v = lp[u];
        v += __shfl_xor(v, 16, 64);
        v += __shfl_xor(v, 32, 64);
        lp[u] = v;
    }

    // streaming per-wave partial: tile = qb*4 + w owns rows [r0, r0+64)
    const int task = (qb * 4 + w) * 16 + bg;
    float* Ob = Opart + (size_t)task * 4096;
    #pragma unroll
    for (int u = 0; u < 4; ++u)
        #pragma unroll
        for (int n = 0; n < 4; ++n)
            #pragma unroll
            for (int r = 0; r < 4; ++r)
                Ob[(u * 16 + quad * 4 + r) * 64 + n * 16 + l16] = of[u][n][r];
    if (quad == 0) {
        #pragma unroll
        for (int u = 0; u < 4; ++u)
            lpart[task * 64 + u * 16 + l16] = lp[u];
    }
}

// ---------------------------------------------------------------------------
// Kernel 3: combine 16 partials/tile (64-row tiles), divide by l,
// l2-normalize -> qnb (bf16). grid = 2048 x 256. Block 0 also zeroes the
// 16KB output (runs before sim's atomics; saves the memset dispatch).
__global__ __launch_bounds__(256) void combine_kernel(
    const float* __restrict__ Opart, const float* __restrict__ lpart,
    __hip_bfloat16* __restrict__ qnb, float* __restrict__ outz)
{
    if (blockIdx.x == 0) {
        #pragma unroll
        for (int z = 0; z < 4; ++z)
            ((float4*)outz)[threadIdx.x * 4 + z] = (float4){0.f, 0.f, 0.f, 0.f};
    }

    const int r    = blockIdx.x * 4 + (threadIdx.x >> 6);
    const int c    = threadIdx.x & 63;
    const int tile = r >> 6, row = r & 63;
    float acc = 0.f, lsum = 0.f;
    #pragma unroll
    for (int g = 0; g < 16; ++g) {
        int task = tile * 16 + g;
        acc  += Opart[(size_t)task * 4096 + row * 64 + c];
        lsum += lpart[task * 64 + row];
    }
    float q = acc / lsum;
    float ss = q * q;
    ss += __shfl_xor(ss, 1, 64);
    ss += __shfl_xor(ss, 2, 64);
    ss += __shfl_xor(ss, 4, 64);
    ss += __shfl_xor(ss, 8, 64);
    ss += __shfl_xor(ss, 16, 64);
    ss += __shfl_xor(ss, 32, 64);
    qnb[(size_t)r * 64 + c] = __float2bfloat16(q * rsqrtf(fmaxf(ss, 1e-24f)));
}

// ---------------------------------------------------------------------------
// Kernel 4: sim = (1/128) * Vn(64x8192) @ Qn(64x8192)^T, split-K MFMA GEMM.
// grid = 64 blocks x 256: each wave owns ONE 32-k slice (16 MFMAs);
// atomicAdd merge (4K addresses).
__global__ __launch_bounds__(256) void sim_kernel(
    const __hip_bfloat16* __restrict__ vnb,
    const __hip_bfloat16* __restrict__ qnb,
    float* __restrict__ out)
{
    const int w    = threadIdx.x >> 6;
    const int lane = threadIdx.x & 63;
    const int l16  = lane & 15;
    const int quad = lane >> 4;
    const int k0   = blockIdx.x * 128 + w * 32 + quad * 8;

    f32x4 acc[4][4];
    #pragma unroll
    for (int mi = 0; mi < 4; ++mi)
        #pragma unroll
        for (int ni = 0; ni < 4; ++ni)
            acc[mi][ni] = (f32x4){0.f, 0.f, 0.f, 0.f};

    bf16x8 af[4], bfv[4];
    #pragma unroll
    for (int mi = 0; mi < 4; ++mi)
        af[mi] = *(const bf16x8*)(vnb + (size_t)(mi * 16 + l16) * 8192 + k0);
    #pragma unroll
    for (int ni = 0; ni < 4; ++ni)
        bfv[ni] = *(const bf16x8*)(qnb + (size_t)(ni * 16 + l16) * 8192 + k0);
    #pragma unroll
    for (int mi = 0; mi < 4; ++mi)
        #pragma unroll
        for (int ni = 0; ni < 4; ++ni)
            acc[mi][ni] = mfma16(af[mi], bfv[ni], acc[mi][ni]);

    #pragma unroll
    for (int mi = 0; mi < 4; ++mi)
        #pragma unroll
        for (int ni = 0; ni < 4; ++ni)
            #pragma unroll
            for (int r = 0; r < 4; ++r)
                atomicAdd(&out[(mi * 16 + quad * 4 + r) * 64 + ni * 16 + l16],
                          acc[mi][ni][r] * (1.f / 128.f));
}

// ---------------------------------------------------------------------------
extern "C" void kernel_launch(void* const* d_in, const int* in_sizes, int n_in,
                              void* d_out, int out_size, void* d_ws, size_t ws_size,
                              hipStream_t stream)
{
    const float* feat = (const float*)d_in[0];
    const float* Wq   = (const float*)d_in[1];
    const float* bq   = (const float*)d_in[2];
    const float* Wk   = (const float*)d_in[3];
    const float* bk   = (const float*)d_in[4];
    const float* Wv   = (const float*)d_in[5];
    const float* bv   = (const float*)d_in[6];
    float* out = (float*)d_out;

    const size_t MB = 1u << 20;
    char* ws = (char*)d_ws;
    __hip_bfloat16* qbf = (__hip_bfloat16*)(ws);              // 1 MB (frag-tiled, pre-scaled)
    __hip_bfloat16* kbf = (__hip_bfloat16*)(ws + 1 * MB);     // 1 MB (fragment-linear)
    __hip_bfloat16* vbf = (__hip_bfloat16*)(ws + 2 * MB);     // 1 MB (fragment-linear)
    __hip_bfloat16* vnb = (__hip_bfloat16*)(ws + 3 * MB);     // 1 MB (row-major)
    float* Opart = (float*)(ws + 4 * MB);                     // 32 MB (2048 x 16 KB)
    float* lpart = (float*)(ws + 36 * MB);                    // 512 KB
    __hip_bfloat16* qnb = (__hip_bfloat16*)(ws + 37 * MB);    // 1 MB

    proj_kernel<<<256, 256, 0, stream>>>(feat, Wq, bq, Wk, bk, Wv, bv, qbf, kbf, vbf, vnb);
    attn_kernel<<<512, 256, 0, stream>>>(qbf, kbf, vbf, Opart, lpart);
    combine_kernel<<<2048, 256, 0, stream>>>(Opart, lpart, qnb, out);
    sim_kernel<<<64, 256, 0, stream>>>(vnb, qnb, out);
}